// Round 6
// baseline (361.887 us; speedup 1.0000x reference)
//
#include <hip/hip_runtime.h>

// Node model GNN, CSR-pull + MFMA edge MLP + wave segmented-reduce:
//   edge MLP: h = relu(relu([x[src],ea]@W1+b1)@W2+b2)   (W3 commuted past the mean)
//   agg[n][j] = sum_{e: dst(e)=n} h[e][j]
//   node: out = relu(mean@(W3@W4mid) + x-terms + (b4+b3@W4mid))@W5+b5   (W3 folded)
// Sort payload is only (dst,e) 8B; edge kernel re-gathers ea/x from cache-resident arrays.
constexpr int HID = 64;

typedef __attribute__((ext_vector_type(8))) short s8v;    // 8 bf16 (4 VGPR) MFMA A/B frag
typedef __attribute__((ext_vector_type(4))) float f32x4;  // MFMA C/D frag
typedef unsigned long long ull;

__device__ __forceinline__ void atomF(float* p, float v) {
    __hip_atomic_fetch_add(p, v, __ATOMIC_RELAXED, __HIP_MEMORY_SCOPE_AGENT);
}

// ---------- pass 0a: split W2 into transposed bf16 hi/lo tables ----------
__global__ __launch_bounds__(64) void pack_w2_kernel(
    const float* __restrict__ W2, unsigned short* __restrict__ Bhi,
    unsigned short* __restrict__ Blo)
{
    const int f = blockIdx.x;    // 64 blocks
    const int k = threadIdx.x;   // 64 threads
    const float w = W2[k * 64 + f];
    const unsigned int u = __float_as_uint(w);
    const float hf = __uint_as_float(u & 0xffff0000u);
    const float r = w - hf;
    Bhi[f * 64 + k] = (unsigned short)(u >> 16);
    Blo[f * 64 + k] = (unsigned short)(__float_as_uint(r) >> 16);
}

// ---------- pass 0b: fold W3 into W4's middle rows ----------
__global__ __launch_bounds__(128) void pack_w34_kernel(
    const float* __restrict__ W3, const float* __restrict__ b3,
    const float* __restrict__ W4, const float* __restrict__ b4,
    float* __restrict__ C, float* __restrict__ b4p)
{
    const int t = blockIdx.x;    // 0..64; t==64 computes the folded bias
    const int j = threadIdx.x;
    if (j >= 67) return;
    if (t < 64) {
        float s = 0.f;
        for (int k = 0; k < 64; ++k) s = fmaf(W3[t * 64 + k], W4[(2 + k) * 67 + j], s);
        C[t * 67 + j] = s;
    } else {
        float s = b4[j];
        for (int k = 0; k < 64; ++k) s = fmaf(b3[k], W4[(2 + k) * 67 + j], s);
        b4p[j] = s;
    }
}

// ---------- pass 1: in-degree histogram ----------
__global__ __launch_bounds__(256) void count_kernel(
    const int* __restrict__ ei, int* __restrict__ counts, int E)
{
    int e = blockIdx.x * 256 + threadIdx.x;
    if (e < E) atomicAdd(&counts[ei[E + e]], 1);
}

// ---------- pass 2a ----------
__global__ __launch_bounds__(256) void scan1_kernel(
    const int* __restrict__ counts, int* __restrict__ partials, int N)
{
    __shared__ int red[256];
    const int base = blockIdx.x * 1024;
    int s = 0;
    #pragma unroll
    for (int r = 0; r < 4; ++r) {
        int i = base + r * 256 + threadIdx.x;
        s += (i < N) ? counts[i] : 0;
    }
    red[threadIdx.x] = s;
    __syncthreads();
    for (int off = 128; off > 0; off >>= 1) {
        if (threadIdx.x < off) red[threadIdx.x] += red[threadIdx.x + off];
        __syncthreads();
    }
    if (threadIdx.x == 0) partials[blockIdx.x] = red[0];
}

// ---------- pass 2b ----------
__global__ __launch_bounds__(256) void scan2_kernel(
    int* __restrict__ partials, int nb, int* __restrict__ offsets, int N)
{
    __shared__ int sm[256];
    __shared__ int carry_s;
    if (threadIdx.x == 0) carry_s = 0;
    __syncthreads();
    for (int base = 0; base < nb; base += 256) {
        int i = base + threadIdx.x;
        int v = (i < nb) ? partials[i] : 0;
        sm[threadIdx.x] = v;
        __syncthreads();
        for (int off = 1; off < 256; off <<= 1) {
            int t = (threadIdx.x >= off) ? sm[threadIdx.x - off] : 0;
            __syncthreads();
            sm[threadIdx.x] += t;
            __syncthreads();
        }
        int incl = sm[threadIdx.x];
        int carry = carry_s;
        __syncthreads();
        if (i < nb) partials[i] = incl - v + carry;
        if (threadIdx.x == 255) carry_s = carry + incl;
        __syncthreads();
    }
    if (threadIdx.x == 0) offsets[N] = carry_s;
}

// ---------- pass 2c ----------
__global__ __launch_bounds__(256) void scan3_kernel(
    const int* __restrict__ counts, const int* __restrict__ partials,
    int* __restrict__ offsets, int* __restrict__ cursor, int N)
{
    __shared__ int sm[256];
    const int tid = threadIdx.x;
    const int i0 = blockIdx.x * 1024 + tid * 4;
    int v[4];
    #pragma unroll
    for (int r = 0; r < 4; ++r) v[r] = (i0 + r < N) ? counts[i0 + r] : 0;
    const int tsum = v[0] + v[1] + v[2] + v[3];
    sm[tid] = tsum;
    __syncthreads();
    for (int off = 1; off < 256; off <<= 1) {
        int t = (tid >= off) ? sm[tid - off] : 0;
        __syncthreads();
        sm[tid] += t;
        __syncthreads();
    }
    int excl = sm[tid] - tsum + partials[blockIdx.x];
    #pragma unroll
    for (int r = 0; r < 4; ++r) {
        if (i0 + r < N) { offsets[i0 + r] = excl; cursor[i0 + r] = excl; }
        excl += v[r];
    }
}

// ---------- pass 3: dest-sort the edge IDs only (8B payload, LLC-merged scatter) ----------
__global__ __launch_bounds__(256) void fill_kernel(
    const int* __restrict__ ei, int* __restrict__ cursor,
    uint2* __restrict__ sidx, int E)
{
    int e = blockIdx.x * 256 + threadIdx.x;
    if (e >= E) return;
    const int dst = ei[E + e];
    const int pos = atomicAdd(&cursor[dst], 1);
    sidx[pos] = make_uint2((unsigned)dst, (unsigned)e);
}

// ---------- pass 4: MFMA edge MLP + wave segmented reduce (8KB LDS/wave) ----------
__global__ __launch_bounds__(128, 4) void edge_mlp_kernel(
    const uint2* __restrict__ sidx,
    const int* __restrict__ ei, const float* __restrict__ x,
    const float* __restrict__ ea,
    const float* __restrict__ W1, const float* __restrict__ b1,
    const unsigned short* __restrict__ Bhi, const unsigned short* __restrict__ Blo,
    const float* __restrict__ b2,
    float* __restrict__ agg, int E)
{
    __shared__ __align__(16) unsigned int smem[2 * 2048];   // 8KB per wave
    const int tid  = threadIdx.x;
    const int wv   = tid >> 6;
    const int lane = tid & 63;
    unsigned int* ws = smem + wv * 2048;
    char* wsb = (char*)ws;

    const int i = blockIdx.x * 128 + wv * 64 + lane;
    int dst = -1;
    float gx0 = 0.f, gx1 = 0.f, gea = 0.f;
    if (i < E) {
        const uint2 de = sidx[i];
        dst = (int)de.x;
        const int eo = (int)de.y;
        gea = ea[eo];                      // L2/LLC gather
        const int src = ei[eo];            // L2/LLC gather
        const float2 xv = ((const float2*)x)[src];  // L2 gather (800KB)
        gx0 = xv.x; gx1 = xv.y;
    }

    const int dprev = __shfl_up(dst, 1);
    const bool startb = (lane == 0) || (dprev != dst);
    const ull bmask = __ballot(startb);
    const ull fmask = (bmask >> 1) | (1ull << 63);

    const int am = lane & 15, aq = lane >> 4;
    const int rsw = (lane & 7) << 4;

    f32x4 acc[4][4];
    #pragma unroll
    for (int a = 0; a < 4; ++a)
        #pragma unroll
        for (int b = 0; b < 4; ++b) acc[a][b] = (f32x4){0.f, 0.f, 0.f, 0.f};

    #pragma unroll
    for (int kb = 0; kb < 2; ++kb) {
        // phase 1: feats kb*32..+31; per-edge 128B row = [hi 64B | lo 64B], XOR-swizzled
        #pragma unroll
        for (int jc = 0; jc < 4; ++jc) {
            unsigned int hp[4], lp[4];
            #pragma unroll
            for (int jp = 0; jp < 4; ++jp) {
                const int j0 = kb * 32 + jc * 8 + jp * 2;
                float v0 = fmaf(gx0, W1[j0],     fmaf(gx1, W1[64 + j0],     fmaf(gea, W1[128 + j0],     b1[j0])));
                float v1 = fmaf(gx0, W1[j0 + 1], fmaf(gx1, W1[64 + j0 + 1], fmaf(gea, W1[128 + j0 + 1], b1[j0 + 1])));
                v0 = fmaxf(v0, 0.f); v1 = fmaxf(v1, 0.f);
                const unsigned int u0 = __float_as_uint(v0), u1 = __float_as_uint(v1);
                hp[jp] = (u0 >> 16) | (u1 & 0xffff0000u);
                const float r0 = v0 - __uint_as_float(u0 & 0xffff0000u);
                const float r1 = v1 - __uint_as_float(u1 & 0xffff0000u);
                lp[jp] = (__float_as_uint(r0) >> 16) | (__float_as_uint(r1) & 0xffff0000u);
            }
            const int boff = (lane * 128 + jc * 16) ^ rsw;
            *(uint4*)(wsb + boff)        = make_uint4(hp[0], hp[1], hp[2], hp[3]);
            *(uint4*)(wsb + (boff ^ 64)) = make_uint4(lp[0], lp[1], lp[2], lp[3]);
        }

        s8v ah[4], al[4], bh[4], bl[4];
        #pragma unroll
        for (int eb = 0; eb < 4; ++eb) {
            const int ar = eb * 16 + am;
            const int ao = (ar * 128 + aq * 16) ^ ((ar & 7) << 4);
            ah[eb] = *(const s8v*)(wsb + ao);
            al[eb] = *(const s8v*)(wsb + (ao ^ 64));
        }
        #pragma unroll
        for (int fb = 0; fb < 4; ++fb) {
            const int bo = (fb * 16 + am) * 64 + kb * 32 + aq * 8;
            bh[fb] = *(const s8v*)(Bhi + bo);
            bl[fb] = *(const s8v*)(Blo + bo);
        }
        asm volatile("" ::: "memory");   // keep next-kb stores after this kb's LDS reads

        #pragma unroll
        for (int eb = 0; eb < 4; ++eb)
            #pragma unroll
            for (int fb = 0; fb < 4; ++fb) {
                acc[eb][fb] = __builtin_amdgcn_mfma_f32_16x16x32_bf16(ah[eb], bh[fb], acc[eb][fb], 0, 0, 0);
                acc[eb][fb] = __builtin_amdgcn_mfma_f32_16x16x32_bf16(ah[eb], bl[fb], acc[eb][fb], 0, 0, 0);
                acc[eb][fb] = __builtin_amdgcn_mfma_f32_16x16x32_bf16(al[eb], bh[fb], acc[eb][fb], 0, 0, 0);
            }
    }

    // phase 3+4 in two 32-edge halves, reusing the same 8KB
    float bias[4];
    #pragma unroll
    for (int fb = 0; fb < 4; ++fb) bias[fb] = b2[fb * 16 + am];

    const int fx = lane & 31;
    float a2 = 0.f;
    #pragma unroll
    for (int h = 0; h < 2; ++h) {
        asm volatile("" ::: "memory");
        #pragma unroll
        for (int ebh = 0; ebh < 2; ++ebh) {
            const int eb = h * 2 + ebh;
            #pragma unroll
            for (int fb = 0; fb < 4; ++fb) {
                const int feat = fb * 16 + am;
                #pragma unroll
                for (int r = 0; r < 4; ++r) {
                    const int eh = ebh * 16 + aq * 4 + r;
                    const float v = fmaxf(acc[eb][fb][r] + bias[fb], 0.f);
                    ws[feat * 32 + (eh ^ (feat & 31))] = __float_as_uint(v);
                }
            }
        }
        asm volatile("" ::: "memory");
        #pragma unroll
        for (int eh = 0; eh < 32; ++eh) {
            const int e2 = h * 32 + eh;
            a2 += __uint_as_float(ws[lane * 32 + (eh ^ fx)]);
            if ((fmask >> e2) & 1ull) {                     // wave-uniform
                const int d = __shfl(dst, e2);
                if (d >= 0) atomF(&agg[(size_t)d * HID + lane], a2);
                a2 = 0.f;
            }
        }
    }
}

// ---------- pass 5: node MLP (W3 pre-folded into C) ----------
__global__ __launch_bounds__(256) void node_kernel(
    const float* __restrict__ x, const float* __restrict__ u,
    const int* __restrict__ batch,
    const float* __restrict__ W4, const float* __restrict__ W5,
    const float* __restrict__ b5,
    const float* __restrict__ C, const float* __restrict__ b4p,
    const float* __restrict__ agg, const int* __restrict__ counts,
    float* __restrict__ out, int N)
{
    const int n = blockIdx.x * 256 + threadIdx.x;
    if (n >= N) return;

    const float inv = 1.f / fmaxf((float)counts[n], 1.f);
    const float4* ar = (const float4*)(agg + (size_t)n * HID);

    float acc[67];
    #pragma unroll
    for (int j = 0; j < 67; ++j) acc[j] = b4p[j];

    #pragma unroll 4
    for (int q = 0; q < 16; ++q) {
        const float4 m4 = ar[q];
        const float mk[4] = {m4.x * inv, m4.y * inv, m4.z * inv, m4.w * inv};
        #pragma unroll
        for (int r = 0; r < 4; ++r) {
            const float* cr = C + (q * 4 + r) * 67;
            #pragma unroll
            for (int j = 0; j < 67; ++j) acc[j] = fmaf(mk[r], cr[j], acc[j]);
        }
    }

    const float2 xv = ((const float2*)x)[n];
    const float ub = u[batch[n]];
    #pragma unroll
    for (int j = 0; j < 67; ++j) acc[j] = fmaf(xv.x, W4[j], acc[j]);
    #pragma unroll
    for (int j = 0; j < 67; ++j) acc[j] = fmaf(xv.y, W4[67 + j], acc[j]);
    #pragma unroll
    for (int j = 0; j < 67; ++j) acc[j] = fmaf(ub, W4[66 * 67 + j], acc[j]);

    float o0 = b5[0], o1 = b5[1];
    #pragma unroll
    for (int j = 0; j < 67; ++j) {
        const float z = fmaxf(acc[j], 0.f);
        o0 = fmaf(z, W5[2 * j], o0);
        o1 = fmaf(z, W5[2 * j + 1], o1);
    }
    out[2 * n] = o0;
    out[2 * n + 1] = o1;
}

extern "C" void kernel_launch(void* const* d_in, const int* in_sizes, int n_in,
                              void* d_out, int out_size, void* d_ws, size_t ws_size,
                              hipStream_t stream) {
    const float* x     = (const float*)d_in[0];
    const int*   ei    = (const int*)  d_in[1];
    const float* ea    = (const float*)d_in[2];
    const float* u     = (const float*)d_in[3];
    const int*   batch = (const int*)  d_in[4];
    const float* W1 = (const float*)d_in[5];  const float* b1 = (const float*)d_in[6];
    const float* W2 = (const float*)d_in[7];  const float* b2 = (const float*)d_in[8];
    const float* W3 = (const float*)d_in[9];  const float* b3 = (const float*)d_in[10];
    const float* W4 = (const float*)d_in[11]; const float* b4 = (const float*)d_in[12];
    const float* W5 = (const float*)d_in[13]; const float* b5 = (const float*)d_in[14];

    const int N = in_sizes[0] / 2;   // 100000
    const int E = in_sizes[2];       // 1600000

    // workspace layout
    char* w = (char*)d_ws;
    size_t o = 0;
    int* counts   = (int*)(w + o); o += (size_t)N * 4;
    int* offsets  = (int*)(w + o); o += (size_t)(N + 1) * 4;
    int* cursor   = (int*)(w + o); o += (size_t)N * 4;
    int* partials = (int*)(w + o); o += 4096 * 4;
    o = (o + 15) & ~(size_t)15;
    unsigned short* Bhi = (unsigned short*)(w + o); o += 64 * 64 * 2;
    unsigned short* Blo = (unsigned short*)(w + o); o += 64 * 64 * 2;
    float* Cmat = (float*)(w + o); o += 64 * 67 * 4;
    float* b4p  = (float*)(w + o); o += 68 * 4;
    o = (o + 15) & ~(size_t)15;
    uint2* sidx   = (uint2*)(w + o); o += (size_t)E * 8;
    float* agg    = (float*)(w + o); o += (size_t)N * HID * 4;

    const int nb1 = (N + 1023) / 1024;

    hipMemsetAsync(counts, 0, (size_t)N * 4, stream);
    hipMemsetAsync(agg, 0, (size_t)N * HID * 4, stream);
    pack_w2_kernel<<<64, 64, 0, stream>>>(W2, Bhi, Blo);
    pack_w34_kernel<<<65, 128, 0, stream>>>(W3, b3, W4, b4, Cmat, b4p);
    count_kernel<<<(E + 255) / 256, 256, 0, stream>>>(ei, counts, E);
    scan1_kernel<<<nb1, 256, 0, stream>>>(counts, partials, N);
    scan2_kernel<<<1, 256, 0, stream>>>(partials, nb1, offsets, N);
    scan3_kernel<<<nb1, 256, 0, stream>>>(counts, partials, offsets, cursor, N);
    fill_kernel<<<(E + 255) / 256, 256, 0, stream>>>(ei, cursor, sidx, E);
    edge_mlp_kernel<<<(E + 127) / 128, 128, 0, stream>>>(sidx, ei, x, ea, W1, b1, Bhi, Blo, b2, agg, E);
    node_kernel<<<(N + 255) / 256, 256, 0, stream>>>(x, u, batch, W4, W5, b5, Cmat, b4p,
                                                     agg, counts, (float*)d_out, N);
}

// Round 7
// 285.686 us; speedup vs baseline: 1.2667x; 1.2667x over previous
//
#include <hip/hip_runtime.h>

// Node model GNN, CSR-pull + MFMA edge MLP + wave segmented-reduce:
//   edge MLP: h = relu(relu([x[src],ea]@W1+b1)@W2+b2)   (W3 commuted past the mean)
//   agg[n][j] = sum_{e: dst(e)=n} h[e][j]
//   node: out = relu(mean@(W3@W4mid) + x-terms + (b4+b3@W4mid))@W5+b5   (W3 folded)
// Grouping by dst via two-level binned counting sort (line-merged scatters):
//   F1: multi-split into 512-node buckets (LDS hist + reserve + rank) -> A
//   F2: per-bucket dst-exact placement in L2-hot 64KB window -> B=(dst,e)
constexpr int HID = 64;
constexpr int BN_SHIFT = 9;            // 512 nodes per coarse bucket
constexpr int CH = 8192;               // edges per F1 workgroup

typedef __attribute__((ext_vector_type(8))) short s8v;    // 8 bf16 (4 VGPR) MFMA A/B frag
typedef __attribute__((ext_vector_type(4))) float f32x4;  // MFMA C/D frag
typedef unsigned long long ull;

__device__ __forceinline__ void atomF(float* p, float v) {
    __hip_atomic_fetch_add(p, v, __ATOMIC_RELAXED, __HIP_MEMORY_SCOPE_AGENT);
}

// ---------- pass 0a: split W2 into transposed bf16 hi/lo tables ----------
__global__ __launch_bounds__(64) void pack_w2_kernel(
    const float* __restrict__ W2, unsigned short* __restrict__ Bhi,
    unsigned short* __restrict__ Blo)
{
    const int f = blockIdx.x;    // 64 blocks
    const int k = threadIdx.x;   // 64 threads
    const float w = W2[k * 64 + f];
    const unsigned int u = __float_as_uint(w);
    const float hf = __uint_as_float(u & 0xffff0000u);
    const float r = w - hf;
    Bhi[f * 64 + k] = (unsigned short)(u >> 16);
    Blo[f * 64 + k] = (unsigned short)(__float_as_uint(r) >> 16);
}

// ---------- pass 0b: fold W3 into W4's middle rows ----------
__global__ __launch_bounds__(128) void pack_w34_kernel(
    const float* __restrict__ W3, const float* __restrict__ b3,
    const float* __restrict__ W4, const float* __restrict__ b4,
    float* __restrict__ C, float* __restrict__ b4p)
{
    const int t = blockIdx.x;    // 0..64; t==64 computes the folded bias
    const int j = threadIdx.x;
    if (j >= 67) return;
    if (t < 64) {
        float s = 0.f;
        for (int k = 0; k < 64; ++k) s = fmaf(W3[t * 64 + k], W4[(2 + k) * 67 + j], s);
        C[t * 67 + j] = s;
    } else {
        float s = b4[j];
        for (int k = 0; k < 64; ++k) s = fmaf(b3[k], W4[(2 + k) * 67 + j], s);
        b4p[j] = s;
    }
}

// ---------- pass 1: in-degree histogram ----------
__global__ __launch_bounds__(256) void count_kernel(
    const int* __restrict__ ei, int* __restrict__ counts, int E)
{
    int e = blockIdx.x * 256 + threadIdx.x;
    if (e < E) atomicAdd(&counts[ei[E + e]], 1);
}

// ---------- pass 2a ----------
__global__ __launch_bounds__(256) void scan1_kernel(
    const int* __restrict__ counts, int* __restrict__ partials, int N)
{
    __shared__ int red[256];
    const int base = blockIdx.x * 1024;
    int s = 0;
    #pragma unroll
    for (int r = 0; r < 4; ++r) {
        int i = base + r * 256 + threadIdx.x;
        s += (i < N) ? counts[i] : 0;
    }
    red[threadIdx.x] = s;
    __syncthreads();
    for (int off = 128; off > 0; off >>= 1) {
        if (threadIdx.x < off) red[threadIdx.x] += red[threadIdx.x + off];
        __syncthreads();
    }
    if (threadIdx.x == 0) partials[blockIdx.x] = red[0];
}

// ---------- pass 2b ----------
__global__ __launch_bounds__(256) void scan2_kernel(
    int* __restrict__ partials, int nb, int* __restrict__ offsets, int N)
{
    __shared__ int sm[256];
    __shared__ int carry_s;
    if (threadIdx.x == 0) carry_s = 0;
    __syncthreads();
    for (int base = 0; base < nb; base += 256) {
        int i = base + threadIdx.x;
        int v = (i < nb) ? partials[i] : 0;
        sm[threadIdx.x] = v;
        __syncthreads();
        for (int off = 1; off < 256; off <<= 1) {
            int t = (threadIdx.x >= off) ? sm[threadIdx.x - off] : 0;
            __syncthreads();
            sm[threadIdx.x] += t;
            __syncthreads();
        }
        int incl = sm[threadIdx.x];
        int carry = carry_s;
        __syncthreads();
        if (i < nb) partials[i] = incl - v + carry;
        if (threadIdx.x == 255) carry_s = carry + incl;
        __syncthreads();
    }
    if (threadIdx.x == 0) offsets[N] = carry_s;
}

// ---------- pass 2c ----------
__global__ __launch_bounds__(256) void scan3_kernel(
    const int* __restrict__ counts, const int* __restrict__ partials,
    int* __restrict__ offsets, int N)
{
    __shared__ int sm[256];
    const int tid = threadIdx.x;
    const int i0 = blockIdx.x * 1024 + tid * 4;
    int v[4];
    #pragma unroll
    for (int r = 0; r < 4; ++r) v[r] = (i0 + r < N) ? counts[i0 + r] : 0;
    const int tsum = v[0] + v[1] + v[2] + v[3];
    sm[tid] = tsum;
    __syncthreads();
    for (int off = 1; off < 256; off <<= 1) {
        int t = (tid >= off) ? sm[tid - off] : 0;
        __syncthreads();
        sm[tid] += t;
        __syncthreads();
    }
    int excl = sm[tid] - tsum + partials[blockIdx.x];
    #pragma unroll
    for (int r = 0; r < 4; ++r) {
        if (i0 + r < N) offsets[i0 + r] = excl;
        excl += v[r];
    }
}

// ---------- pass 2d: bucket cursors = offsets at bucket bases ----------
__global__ __launch_bounds__(256) void init_bcur_kernel(
    const int* __restrict__ offsets, int* __restrict__ bcur, int NB)
{
    int b = threadIdx.x + blockIdx.x * 256;
    if (b < NB) bcur[b] = offsets[b << BN_SHIFT];
}

// ---------- pass 3a: multi-split into coarse buckets (merged writes) ----------
__global__ __launch_bounds__(256) void binA_kernel(
    const int* __restrict__ ei, int* __restrict__ bcur,
    uint2* __restrict__ A, int E, int NB)
{
    __shared__ int hist[256];
    __shared__ int base_s[256];
    const int tid = threadIdx.x;
    const int e0 = blockIdx.x * CH;

    for (int i = tid; i < NB; i += 256) hist[i] = 0;
    __syncthreads();
    #pragma unroll
    for (int r = 0; r < CH / 256; ++r) {
        const int e = e0 + r * 256 + tid;
        if (e < E) atomicAdd(&hist[ei[E + e] >> BN_SHIFT], 1);
    }
    __syncthreads();
    for (int i = tid; i < NB; i += 256) {
        const int h = hist[i];
        base_s[i] = h ? atomicAdd(&bcur[i], h) : 0;   // one reservation per (block,bucket)
        hist[i] = 0;                                   // reuse as local rank cursor
    }
    __syncthreads();
    #pragma unroll
    for (int r = 0; r < CH / 256; ++r) {
        const int e = e0 + r * 256 + tid;
        if (e < E) {
            const int d = ei[E + e];                   // L2-hot (2nd read of chunk)
            const int b = d >> BN_SHIFT;
            const int pos = base_s[b] + atomicAdd(&hist[b], 1);
            A[pos] = make_uint2((unsigned)d, (unsigned)e);
        }
    }
}

// ---------- pass 3b: dst-exact placement within each bucket's L2-hot window ----------
__global__ __launch_bounds__(256) void binB_kernel(
    const uint2* __restrict__ A, const int* __restrict__ offsets,
    uint2* __restrict__ B, int N)
{
    __shared__ int lcur[1 << BN_SHIFT];
    const int b = blockIdx.x;
    const int lo = b << BN_SHIFT;
    const int span = min(1 << BN_SHIFT, N - lo);
    const int tid = threadIdx.x;
    for (int i = tid; i < span; i += 256) lcur[i] = offsets[lo + i];
    __syncthreads();
    const int start = offsets[lo];
    const int end = offsets[lo + span];
    for (int idx = start + tid; idx < end; idx += 256) {
        const uint2 p = A[idx];
        const int pos = atomicAdd(&lcur[(int)p.x - lo], 1);
        B[pos] = p;
    }
}

// ---------- pass 4: MFMA edge MLP + wave segmented reduce (8KB LDS/wave) ----------
__global__ __launch_bounds__(128, 4) void edge_mlp_kernel(
    const uint2* __restrict__ sidx,
    const int* __restrict__ ei, const float* __restrict__ x,
    const float* __restrict__ ea,
    const float* __restrict__ W1, const float* __restrict__ b1,
    const unsigned short* __restrict__ Bhi, const unsigned short* __restrict__ Blo,
    const float* __restrict__ b2,
    float* __restrict__ agg, int E)
{
    __shared__ __align__(16) unsigned int smem[2 * 2048];   // 8KB per wave
    const int tid  = threadIdx.x;
    const int wv   = tid >> 6;
    const int lane = tid & 63;
    unsigned int* ws = smem + wv * 2048;
    char* wsb = (char*)ws;

    const int i = blockIdx.x * 128 + wv * 64 + lane;
    int dst = -1;
    float gx0 = 0.f, gx1 = 0.f, gea = 0.f;
    if (i < E) {
        const uint2 de = sidx[i];
        dst = (int)de.x;
        const int eo = (int)de.y;
        gea = ea[eo];                               // L2/LLC gather
        const int src = ei[eo];                     // L2/LLC gather
        const float2 xv = ((const float2*)x)[src];  // L2 gather (800KB)
        gx0 = xv.x; gx1 = xv.y;
    }

    const int dprev = __shfl_up(dst, 1);
    const bool startb = (lane == 0) || (dprev != dst);
    const ull bmask = __ballot(startb);
    const ull fmask = (bmask >> 1) | (1ull << 63);

    const int am = lane & 15, aq = lane >> 4;
    const int rsw = (lane & 7) << 4;

    f32x4 acc[4][4];
    #pragma unroll
    for (int a = 0; a < 4; ++a)
        #pragma unroll
        for (int b = 0; b < 4; ++b) acc[a][b] = (f32x4){0.f, 0.f, 0.f, 0.f};

    #pragma unroll
    for (int kb = 0; kb < 2; ++kb) {
        // phase 1: feats kb*32..+31; per-edge 128B row = [hi 64B | lo 64B], XOR-swizzled
        #pragma unroll
        for (int jc = 0; jc < 4; ++jc) {
            unsigned int hp[4], lp[4];
            #pragma unroll
            for (int jp = 0; jp < 4; ++jp) {
                const int j0 = kb * 32 + jc * 8 + jp * 2;
                float v0 = fmaf(gx0, W1[j0],     fmaf(gx1, W1[64 + j0],     fmaf(gea, W1[128 + j0],     b1[j0])));
                float v1 = fmaf(gx0, W1[j0 + 1], fmaf(gx1, W1[64 + j0 + 1], fmaf(gea, W1[128 + j0 + 1], b1[j0 + 1])));
                v0 = fmaxf(v0, 0.f); v1 = fmaxf(v1, 0.f);
                const unsigned int u0 = __float_as_uint(v0), u1 = __float_as_uint(v1);
                hp[jp] = (u0 >> 16) | (u1 & 0xffff0000u);
                const float r0 = v0 - __uint_as_float(u0 & 0xffff0000u);
                const float r1 = v1 - __uint_as_float(u1 & 0xffff0000u);
                lp[jp] = (__float_as_uint(r0) >> 16) | (__float_as_uint(r1) & 0xffff0000u);
            }
            const int boff = (lane * 128 + jc * 16) ^ rsw;
            *(uint4*)(wsb + boff)        = make_uint4(hp[0], hp[1], hp[2], hp[3]);
            *(uint4*)(wsb + (boff ^ 64)) = make_uint4(lp[0], lp[1], lp[2], lp[3]);
        }

        s8v ah[4], al[4], bh[4], bl[4];
        #pragma unroll
        for (int eb = 0; eb < 4; ++eb) {
            const int ar = eb * 16 + am;
            const int ao = (ar * 128 + aq * 16) ^ ((ar & 7) << 4);
            ah[eb] = *(const s8v*)(wsb + ao);
            al[eb] = *(const s8v*)(wsb + (ao ^ 64));
        }
        #pragma unroll
        for (int fb = 0; fb < 4; ++fb) {
            const int bo = (fb * 16 + am) * 64 + kb * 32 + aq * 8;
            bh[fb] = *(const s8v*)(Bhi + bo);
            bl[fb] = *(const s8v*)(Blo + bo);
        }
        asm volatile("" ::: "memory");   // keep next-kb stores after this kb's LDS reads

        #pragma unroll
        for (int eb = 0; eb < 4; ++eb)
            #pragma unroll
            for (int fb = 0; fb < 4; ++fb) {
                acc[eb][fb] = __builtin_amdgcn_mfma_f32_16x16x32_bf16(ah[eb], bh[fb], acc[eb][fb], 0, 0, 0);
                acc[eb][fb] = __builtin_amdgcn_mfma_f32_16x16x32_bf16(ah[eb], bl[fb], acc[eb][fb], 0, 0, 0);
                acc[eb][fb] = __builtin_amdgcn_mfma_f32_16x16x32_bf16(al[eb], bh[fb], acc[eb][fb], 0, 0, 0);
            }
    }

    // phase 3+4 in two 32-edge halves, reusing the same 8KB
    float bias[4];
    #pragma unroll
    for (int fb = 0; fb < 4; ++fb) bias[fb] = b2[fb * 16 + am];

    const int fx = lane & 31;
    float a2 = 0.f;
    #pragma unroll
    for (int h = 0; h < 2; ++h) {
        asm volatile("" ::: "memory");
        #pragma unroll
        for (int ebh = 0; ebh < 2; ++ebh) {
            const int eb = h * 2 + ebh;
            #pragma unroll
            for (int fb = 0; fb < 4; ++fb) {
                const int feat = fb * 16 + am;
                #pragma unroll
                for (int r = 0; r < 4; ++r) {
                    const int eh = ebh * 16 + aq * 4 + r;
                    const float v = fmaxf(acc[eb][fb][r] + bias[fb], 0.f);
                    ws[feat * 32 + (eh ^ (feat & 31))] = __float_as_uint(v);
                }
            }
        }
        asm volatile("" ::: "memory");
        #pragma unroll
        for (int eh = 0; eh < 32; ++eh) {
            const int e2 = h * 32 + eh;
            a2 += __uint_as_float(ws[lane * 32 + (eh ^ fx)]);
            if ((fmask >> e2) & 1ull) {                     // wave-uniform
                const int d = __shfl(dst, e2);
                if (d >= 0) atomF(&agg[(size_t)d * HID + lane], a2);
                a2 = 0.f;
            }
        }
    }
}

// ---------- pass 5: node MLP (W3 pre-folded into C) ----------
__global__ __launch_bounds__(256) void node_kernel(
    const float* __restrict__ x, const float* __restrict__ u,
    const int* __restrict__ batch,
    const float* __restrict__ W4, const float* __restrict__ W5,
    const float* __restrict__ b5,
    const float* __restrict__ C, const float* __restrict__ b4p,
    const float* __restrict__ agg, const int* __restrict__ counts,
    float* __restrict__ out, int N)
{
    const int n = blockIdx.x * 256 + threadIdx.x;
    if (n >= N) return;

    const float inv = 1.f / fmaxf((float)counts[n], 1.f);
    const float4* ar = (const float4*)(agg + (size_t)n * HID);

    float acc[67];
    #pragma unroll
    for (int j = 0; j < 67; ++j) acc[j] = b4p[j];

    #pragma unroll 4
    for (int q = 0; q < 16; ++q) {
        const float4 m4 = ar[q];
        const float mk[4] = {m4.x * inv, m4.y * inv, m4.z * inv, m4.w * inv};
        #pragma unroll
        for (int r = 0; r < 4; ++r) {
            const float* cr = C + (q * 4 + r) * 67;
            #pragma unroll
            for (int j = 0; j < 67; ++j) acc[j] = fmaf(mk[r], cr[j], acc[j]);
        }
    }

    const float2 xv = ((const float2*)x)[n];
    const float ub = u[batch[n]];
    #pragma unroll
    for (int j = 0; j < 67; ++j) acc[j] = fmaf(xv.x, W4[j], acc[j]);
    #pragma unroll
    for (int j = 0; j < 67; ++j) acc[j] = fmaf(xv.y, W4[67 + j], acc[j]);
    #pragma unroll
    for (int j = 0; j < 67; ++j) acc[j] = fmaf(ub, W4[66 * 67 + j], acc[j]);

    float o0 = b5[0], o1 = b5[1];
    #pragma unroll
    for (int j = 0; j < 67; ++j) {
        const float z = fmaxf(acc[j], 0.f);
        o0 = fmaf(z, W5[2 * j], o0);
        o1 = fmaf(z, W5[2 * j + 1], o1);
    }
    out[2 * n] = o0;
    out[2 * n + 1] = o1;
}

extern "C" void kernel_launch(void* const* d_in, const int* in_sizes, int n_in,
                              void* d_out, int out_size, void* d_ws, size_t ws_size,
                              hipStream_t stream) {
    const float* x     = (const float*)d_in[0];
    const int*   ei    = (const int*)  d_in[1];
    const float* ea    = (const float*)d_in[2];
    const float* u     = (const float*)d_in[3];
    const int*   batch = (const int*)  d_in[4];
    const float* W1 = (const float*)d_in[5];  const float* b1 = (const float*)d_in[6];
    const float* W2 = (const float*)d_in[7];  const float* b2 = (const float*)d_in[8];
    const float* W3 = (const float*)d_in[9];  const float* b3 = (const float*)d_in[10];
    const float* W4 = (const float*)d_in[11]; const float* b4 = (const float*)d_in[12];
    const float* W5 = (const float*)d_in[13]; const float* b5 = (const float*)d_in[14];

    const int N = in_sizes[0] / 2;   // 100000
    const int E = in_sizes[2];       // 1600000
    const int NB = (N + (1 << BN_SHIFT) - 1) >> BN_SHIFT;   // 196 coarse buckets

    // workspace layout (~52.1 MB)
    char* w = (char*)d_ws;
    size_t o = 0;
    int* counts   = (int*)(w + o); o += (size_t)N * 4;
    int* offsets  = (int*)(w + o); o += (size_t)(N + 1) * 4;
    int* partials = (int*)(w + o); o += 4096 * 4;
    int* bcur     = (int*)(w + o); o += 256 * 4;
    o = (o + 15) & ~(size_t)15;
    unsigned short* Bhi = (unsigned short*)(w + o); o += 64 * 64 * 2;
    unsigned short* Blo = (unsigned short*)(w + o); o += 64 * 64 * 2;
    float* Cmat = (float*)(w + o); o += 64 * 67 * 4;
    float* b4p  = (float*)(w + o); o += 68 * 4;
    o = (o + 15) & ~(size_t)15;
    uint2* Abuf   = (uint2*)(w + o); o += (size_t)E * 8;
    uint2* sidx   = (uint2*)(w + o); o += (size_t)E * 8;
    float* agg    = (float*)(w + o); o += (size_t)N * HID * 4;

    const int nb1 = (N + 1023) / 1024;

    hipMemsetAsync(counts, 0, (size_t)N * 4, stream);
    hipMemsetAsync(agg, 0, (size_t)N * HID * 4, stream);
    pack_w2_kernel<<<64, 64, 0, stream>>>(W2, Bhi, Blo);
    pack_w34_kernel<<<65, 128, 0, stream>>>(W3, b3, W4, b4, Cmat, b4p);
    count_kernel<<<(E + 255) / 256, 256, 0, stream>>>(ei, counts, E);
    scan1_kernel<<<nb1, 256, 0, stream>>>(counts, partials, N);
    scan2_kernel<<<1, 256, 0, stream>>>(partials, nb1, offsets, N);
    scan3_kernel<<<nb1, 256, 0, stream>>>(counts, partials, offsets, N);
    init_bcur_kernel<<<1, 256, 0, stream>>>(offsets, bcur, NB);
    binA_kernel<<<(E + CH - 1) / CH, 256, 0, stream>>>(ei, bcur, Abuf, E, NB);
    binB_kernel<<<NB, 256, 0, stream>>>(Abuf, offsets, sidx, N);
    edge_mlp_kernel<<<(E + 127) / 128, 128, 0, stream>>>(sidx, ei, x, ea, W1, b1, Bhi, Blo, b2, agg, E);
    node_kernel<<<(N + 255) / 256, 256, 0, stream>>>(x, u, batch, W4, W5, b5, Cmat, b4p,
                                                     agg, counts, (float*)d_out, N);
}

// Round 8
// 274.133 us; speedup vs baseline: 1.3201x; 1.0421x over previous
//
#include <hip/hip_runtime.h>

// Node model GNN, CSR-pull + MFMA edge MLP + wave segmented-reduce:
//   edge MLP: h = relu(relu([x[src],ea]@W1+b1)@W2+b2)   (W3 commuted past the mean)
//   agg[n][j] = sum_{e: dst(e)=n} h[e][j]
//   node: out = relu(mean@(W3@W4mid) + x-terms + (b4+b3@W4mid))@W5+b5   (W3 folded)
// Grouping by dst via two-level binned counting sort carrying the full payload
// (gathers only in the sequential binA pass; x is 800KB = L2-resident):
//   binA: stream ei/ea, gather x[src], multi-split float4 records into 512-node buckets
//   binB: dst-exact permute inside the bucket's L2-hot ~128KB window
// agg aliases the A buffer (dead after binB; both 25.6MB).
constexpr int HID = 64;
constexpr int BN_SHIFT = 9;            // 512 nodes per coarse bucket
constexpr int CH = 8192;               // edges per binA workgroup

typedef __attribute__((ext_vector_type(8))) short s8v;    // 8 bf16 (4 VGPR) MFMA A/B frag
typedef __attribute__((ext_vector_type(4))) float f32x4;  // MFMA C/D frag
typedef unsigned long long ull;

__device__ __forceinline__ void atomF(float* p, float v) {
    __hip_atomic_fetch_add(p, v, __ATOMIC_RELAXED, __HIP_MEMORY_SCOPE_AGENT);
}

// ---------- pass 0a: split W2 into transposed bf16 hi/lo tables ----------
__global__ __launch_bounds__(64) void pack_w2_kernel(
    const float* __restrict__ W2, unsigned short* __restrict__ Bhi,
    unsigned short* __restrict__ Blo)
{
    const int f = blockIdx.x;    // 64 blocks
    const int k = threadIdx.x;   // 64 threads
    const float w = W2[k * 64 + f];
    const unsigned int u = __float_as_uint(w);
    const float hf = __uint_as_float(u & 0xffff0000u);
    const float r = w - hf;
    Bhi[f * 64 + k] = (unsigned short)(u >> 16);
    Blo[f * 64 + k] = (unsigned short)(__float_as_uint(r) >> 16);
}

// ---------- pass 0b: fold W3 into W4's middle rows ----------
__global__ __launch_bounds__(128) void pack_w34_kernel(
    const float* __restrict__ W3, const float* __restrict__ b3,
    const float* __restrict__ W4, const float* __restrict__ b4,
    float* __restrict__ C, float* __restrict__ b4p)
{
    const int t = blockIdx.x;    // 0..64; t==64 computes the folded bias
    const int j = threadIdx.x;
    if (j >= 67) return;
    if (t < 64) {
        float s = 0.f;
        for (int k = 0; k < 64; ++k) s = fmaf(W3[t * 64 + k], W4[(2 + k) * 67 + j], s);
        C[t * 67 + j] = s;
    } else {
        float s = b4[j];
        for (int k = 0; k < 64; ++k) s = fmaf(b3[k], W4[(2 + k) * 67 + j], s);
        b4p[j] = s;
    }
}

// ---------- pass 1: in-degree histogram ----------
__global__ __launch_bounds__(256) void count_kernel(
    const int* __restrict__ ei, int* __restrict__ counts, int E)
{
    int e = blockIdx.x * 256 + threadIdx.x;
    if (e < E) atomicAdd(&counts[ei[E + e]], 1);
}

// ---------- pass 2a ----------
__global__ __launch_bounds__(256) void scan1_kernel(
    const int* __restrict__ counts, int* __restrict__ partials, int N)
{
    __shared__ int red[256];
    const int base = blockIdx.x * 1024;
    int s = 0;
    #pragma unroll
    for (int r = 0; r < 4; ++r) {
        int i = base + r * 256 + threadIdx.x;
        s += (i < N) ? counts[i] : 0;
    }
    red[threadIdx.x] = s;
    __syncthreads();
    for (int off = 128; off > 0; off >>= 1) {
        if (threadIdx.x < off) red[threadIdx.x] += red[threadIdx.x + off];
        __syncthreads();
    }
    if (threadIdx.x == 0) partials[blockIdx.x] = red[0];
}

// ---------- pass 2b ----------
__global__ __launch_bounds__(256) void scan2_kernel(
    int* __restrict__ partials, int nb, int* __restrict__ offsets, int N)
{
    __shared__ int sm[256];
    __shared__ int carry_s;
    if (threadIdx.x == 0) carry_s = 0;
    __syncthreads();
    for (int base = 0; base < nb; base += 256) {
        int i = base + threadIdx.x;
        int v = (i < nb) ? partials[i] : 0;
        sm[threadIdx.x] = v;
        __syncthreads();
        for (int off = 1; off < 256; off <<= 1) {
            int t = (threadIdx.x >= off) ? sm[threadIdx.x - off] : 0;
            __syncthreads();
            sm[threadIdx.x] += t;
            __syncthreads();
        }
        int incl = sm[threadIdx.x];
        int carry = carry_s;
        __syncthreads();
        if (i < nb) partials[i] = incl - v + carry;
        if (threadIdx.x == 255) carry_s = carry + incl;
        __syncthreads();
    }
    if (threadIdx.x == 0) offsets[N] = carry_s;
}

// ---------- pass 2c ----------
__global__ __launch_bounds__(256) void scan3_kernel(
    const int* __restrict__ counts, const int* __restrict__ partials,
    int* __restrict__ offsets, int N)
{
    __shared__ int sm[256];
    const int tid = threadIdx.x;
    const int i0 = blockIdx.x * 1024 + tid * 4;
    int v[4];
    #pragma unroll
    for (int r = 0; r < 4; ++r) v[r] = (i0 + r < N) ? counts[i0 + r] : 0;
    const int tsum = v[0] + v[1] + v[2] + v[3];
    sm[tid] = tsum;
    __syncthreads();
    for (int off = 1; off < 256; off <<= 1) {
        int t = (tid >= off) ? sm[tid - off] : 0;
        __syncthreads();
        sm[tid] += t;
        __syncthreads();
    }
    int excl = sm[tid] - tsum + partials[blockIdx.x];
    #pragma unroll
    for (int r = 0; r < 4; ++r) {
        if (i0 + r < N) offsets[i0 + r] = excl;
        excl += v[r];
    }
}

// ---------- pass 2d: bucket cursors = offsets at bucket bases ----------
__global__ __launch_bounds__(256) void init_bcur_kernel(
    const int* __restrict__ offsets, int* __restrict__ bcur, int NB)
{
    int b = threadIdx.x + blockIdx.x * 256;
    if (b < NB) bcur[b] = offsets[b << BN_SHIFT];
}

// ---------- pass 3a: multi-split full payload into coarse buckets (merged writes) ----------
__global__ __launch_bounds__(256) void binA_kernel(
    const int* __restrict__ ei, const float* __restrict__ x,
    const float* __restrict__ ea, int* __restrict__ bcur,
    float4* __restrict__ A, int E, int NB)
{
    __shared__ int hist[256];
    __shared__ int base_s[256];
    const int tid = threadIdx.x;
    const int e0 = blockIdx.x * CH;

    for (int i = tid; i < NB; i += 256) hist[i] = 0;
    __syncthreads();
    #pragma unroll
    for (int r = 0; r < CH / 256; ++r) {
        const int e = e0 + r * 256 + tid;
        if (e < E) atomicAdd(&hist[ei[E + e] >> BN_SHIFT], 1);
    }
    __syncthreads();
    for (int i = tid; i < NB; i += 256) {
        const int h = hist[i];
        base_s[i] = h ? atomicAdd(&bcur[i], h) : 0;   // one reservation per (block,bucket)
        hist[i] = 0;                                   // reuse as local rank cursor
    }
    __syncthreads();
    #pragma unroll
    for (int r = 0; r < CH / 256; ++r) {
        const int e = e0 + r * 256 + tid;
        if (e < E) {
            const int d = ei[E + e];                   // L2-hot (2nd read of chunk)
            const int src = ei[e];                     // sequential stream
            const float w = ea[e];                     // sequential stream
            const float2 xv = ((const float2*)x)[src]; // gather into 800KB (L2-fit)
            const int b = d >> BN_SHIFT;
            const int pos = base_s[b] + atomicAdd(&hist[b], 1);
            A[pos] = make_float4(xv.x, xv.y, w, __int_as_float(d));
        }
    }
}

// ---------- pass 3b: dst-exact permute within each bucket's L2-hot window ----------
__global__ __launch_bounds__(256) void binB_kernel(
    const float4* __restrict__ A, const int* __restrict__ offsets,
    float4* __restrict__ B, int N)
{
    __shared__ int lcur[1 << BN_SHIFT];
    const int b = blockIdx.x;
    const int lo = b << BN_SHIFT;
    const int span = min(1 << BN_SHIFT, N - lo);
    const int tid = threadIdx.x;
    for (int i = tid; i < span; i += 256) lcur[i] = offsets[lo + i];
    __syncthreads();
    const int start = offsets[lo];
    const int end = offsets[lo + span];
    for (int idx = start + tid; idx < end; idx += 256) {
        const float4 p = A[idx];
        const int pos = atomicAdd(&lcur[__float_as_int(p.w) - lo], 1);
        B[pos] = p;
    }
}

// ---------- pass 4: MFMA edge MLP + wave segmented reduce (8KB LDS/wave) ----------
__global__ __launch_bounds__(128, 4) void edge_mlp_kernel(
    const float4* __restrict__ ginp,
    const float* __restrict__ W1, const float* __restrict__ b1,
    const unsigned short* __restrict__ Bhi, const unsigned short* __restrict__ Blo,
    const float* __restrict__ b2,
    float* __restrict__ agg, int E)
{
    __shared__ __align__(16) unsigned int smem[2 * 2048];   // 8KB per wave
    const int tid  = threadIdx.x;
    const int wv   = tid >> 6;
    const int lane = tid & 63;
    unsigned int* ws = smem + wv * 2048;
    char* wsb = (char*)ws;

    const int i = blockIdx.x * 128 + wv * 64 + lane;
    int dst = -1;
    float gx0 = 0.f, gx1 = 0.f, gea = 0.f;
    if (i < E) {
        const float4 g = ginp[i];                    // streaming, LLC-resident
        gx0 = g.x; gx1 = g.y; gea = g.z;
        dst = __float_as_int(g.w);
    }

    const int dprev = __shfl_up(dst, 1);
    const bool startb = (lane == 0) || (dprev != dst);
    const ull bmask = __ballot(startb);
    const ull fmask = (bmask >> 1) | (1ull << 63);

    const int am = lane & 15, aq = lane >> 4;
    const int rsw = (lane & 7) << 4;

    f32x4 acc[4][4];
    #pragma unroll
    for (int a = 0; a < 4; ++a)
        #pragma unroll
        for (int b = 0; b < 4; ++b) acc[a][b] = (f32x4){0.f, 0.f, 0.f, 0.f};

    #pragma unroll
    for (int kb = 0; kb < 2; ++kb) {
        // phase 1: feats kb*32..+31; per-edge 128B row = [hi 64B | lo 64B], XOR-swizzled
        #pragma unroll
        for (int jc = 0; jc < 4; ++jc) {
            unsigned int hp[4], lp[4];
            #pragma unroll
            for (int jp = 0; jp < 4; ++jp) {
                const int j0 = kb * 32 + jc * 8 + jp * 2;
                float v0 = fmaf(gx0, W1[j0],     fmaf(gx1, W1[64 + j0],     fmaf(gea, W1[128 + j0],     b1[j0])));
                float v1 = fmaf(gx0, W1[j0 + 1], fmaf(gx1, W1[64 + j0 + 1], fmaf(gea, W1[128 + j0 + 1], b1[j0 + 1])));
                v0 = fmaxf(v0, 0.f); v1 = fmaxf(v1, 0.f);
                const unsigned int u0 = __float_as_uint(v0), u1 = __float_as_uint(v1);
                hp[jp] = (u0 >> 16) | (u1 & 0xffff0000u);
                const float r0 = v0 - __uint_as_float(u0 & 0xffff0000u);
                const float r1 = v1 - __uint_as_float(u1 & 0xffff0000u);
                lp[jp] = (__float_as_uint(r0) >> 16) | (__float_as_uint(r1) & 0xffff0000u);
            }
            const int boff = (lane * 128 + jc * 16) ^ rsw;
            *(uint4*)(wsb + boff)        = make_uint4(hp[0], hp[1], hp[2], hp[3]);
            *(uint4*)(wsb + (boff ^ 64)) = make_uint4(lp[0], lp[1], lp[2], lp[3]);
        }

        s8v ah[4], al[4], bh[4], bl[4];
        #pragma unroll
        for (int eb = 0; eb < 4; ++eb) {
            const int ar = eb * 16 + am;
            const int ao = (ar * 128 + aq * 16) ^ ((ar & 7) << 4);
            ah[eb] = *(const s8v*)(wsb + ao);
            al[eb] = *(const s8v*)(wsb + (ao ^ 64));
        }
        #pragma unroll
        for (int fb = 0; fb < 4; ++fb) {
            const int bo = (fb * 16 + am) * 64 + kb * 32 + aq * 8;
            bh[fb] = *(const s8v*)(Bhi + bo);
            bl[fb] = *(const s8v*)(Blo + bo);
        }
        asm volatile("" ::: "memory");   // keep next-kb stores after this kb's LDS reads

        #pragma unroll
        for (int eb = 0; eb < 4; ++eb)
            #pragma unroll
            for (int fb = 0; fb < 4; ++fb) {
                acc[eb][fb] = __builtin_amdgcn_mfma_f32_16x16x32_bf16(ah[eb], bh[fb], acc[eb][fb], 0, 0, 0);
                acc[eb][fb] = __builtin_amdgcn_mfma_f32_16x16x32_bf16(ah[eb], bl[fb], acc[eb][fb], 0, 0, 0);
                acc[eb][fb] = __builtin_amdgcn_mfma_f32_16x16x32_bf16(al[eb], bh[fb], acc[eb][fb], 0, 0, 0);
            }
    }

    // phase 3+4 in two 32-edge halves, reusing the same 8KB
    float bias[4];
    #pragma unroll
    for (int fb = 0; fb < 4; ++fb) bias[fb] = b2[fb * 16 + am];

    const int fx = lane & 31;
    float a2 = 0.f;
    #pragma unroll
    for (int h = 0; h < 2; ++h) {
        asm volatile("" ::: "memory");
        #pragma unroll
        for (int ebh = 0; ebh < 2; ++ebh) {
            const int eb = h * 2 + ebh;
            #pragma unroll
            for (int fb = 0; fb < 4; ++fb) {
                const int feat = fb * 16 + am;
                #pragma unroll
                for (int r = 0; r < 4; ++r) {
                    const int eh = ebh * 16 + aq * 4 + r;
                    const float v = fmaxf(acc[eb][fb][r] + bias[fb], 0.f);
                    ws[feat * 32 + (eh ^ (feat & 31))] = __float_as_uint(v);
                }
            }
        }
        asm volatile("" ::: "memory");
        #pragma unroll
        for (int eh = 0; eh < 32; ++eh) {
            const int e2 = h * 32 + eh;
            a2 += __uint_as_float(ws[lane * 32 + (eh ^ fx)]);
            if ((fmask >> e2) & 1ull) {                     // wave-uniform
                const int d = __shfl(dst, e2);
                if (d >= 0) atomF(&agg[(size_t)d * HID + lane], a2);
                a2 = 0.f;
            }
        }
    }
}

// ---------- pass 5: node MLP (W3 pre-folded into C) ----------
__global__ __launch_bounds__(256) void node_kernel(
    const float* __restrict__ x, const float* __restrict__ u,
    const int* __restrict__ batch,
    const float* __restrict__ W4, const float* __restrict__ W5,
    const float* __restrict__ b5,
    const float* __restrict__ C, const float* __restrict__ b4p,
    const float* __restrict__ agg, const int* __restrict__ counts,
    float* __restrict__ out, int N)
{
    const int n = blockIdx.x * 256 + threadIdx.x;
    if (n >= N) return;

    const float inv = 1.f / fmaxf((float)counts[n], 1.f);
    const float4* ar = (const float4*)(agg + (size_t)n * HID);

    float acc[67];
    #pragma unroll
    for (int j = 0; j < 67; ++j) acc[j] = b4p[j];

    #pragma unroll 4
    for (int q = 0; q < 16; ++q) {
        const float4 m4 = ar[q];
        const float mk[4] = {m4.x * inv, m4.y * inv, m4.z * inv, m4.w * inv};
        #pragma unroll
        for (int r = 0; r < 4; ++r) {
            const float* cr = C + (q * 4 + r) * 67;
            #pragma unroll
            for (int j = 0; j < 67; ++j) acc[j] = fmaf(mk[r], cr[j], acc[j]);
        }
    }

    const float2 xv = ((const float2*)x)[n];
    const float ub = u[batch[n]];
    #pragma unroll
    for (int j = 0; j < 67; ++j) acc[j] = fmaf(xv.x, W4[j], acc[j]);
    #pragma unroll
    for (int j = 0; j < 67; ++j) acc[j] = fmaf(xv.y, W4[67 + j], acc[j]);
    #pragma unroll
    for (int j = 0; j < 67; ++j) acc[j] = fmaf(ub, W4[66 * 67 + j], acc[j]);

    float o0 = b5[0], o1 = b5[1];
    #pragma unroll
    for (int j = 0; j < 67; ++j) {
        const float z = fmaxf(acc[j], 0.f);
        o0 = fmaf(z, W5[2 * j], o0);
        o1 = fmaf(z, W5[2 * j + 1], o1);
    }
    out[2 * n] = o0;
    out[2 * n + 1] = o1;
}

extern "C" void kernel_launch(void* const* d_in, const int* in_sizes, int n_in,
                              void* d_out, int out_size, void* d_ws, size_t ws_size,
                              hipStream_t stream) {
    const float* x     = (const float*)d_in[0];
    const int*   ei    = (const int*)  d_in[1];
    const float* ea    = (const float*)d_in[2];
    const float* u     = (const float*)d_in[3];
    const int*   batch = (const int*)  d_in[4];
    const float* W1 = (const float*)d_in[5];  const float* b1 = (const float*)d_in[6];
    const float* W2 = (const float*)d_in[7];  const float* b2 = (const float*)d_in[8];
    const float* W3 = (const float*)d_in[9];  const float* b3 = (const float*)d_in[10];
    const float* W4 = (const float*)d_in[11]; const float* b4 = (const float*)d_in[12];
    const float* W5 = (const float*)d_in[13]; const float* b5 = (const float*)d_in[14];

    const int N = in_sizes[0] / 2;   // 100000
    const int E = in_sizes[2];       // 1600000
    const int NB = (N + (1 << BN_SHIFT) - 1) >> BN_SHIFT;   // 196 coarse buckets

    // workspace layout (~52.2 MB); agg aliases A (A dead after binB, equal 25.6MB)
    char* w = (char*)d_ws;
    size_t o = 0;
    int* counts   = (int*)(w + o); o += (size_t)N * 4;
    int* offsets  = (int*)(w + o); o += (size_t)(N + 1) * 4;
    int* partials = (int*)(w + o); o += 4096 * 4;
    int* bcur     = (int*)(w + o); o += 256 * 4;
    o = (o + 15) & ~(size_t)15;
    unsigned short* Bhi = (unsigned short*)(w + o); o += 64 * 64 * 2;
    unsigned short* Blo = (unsigned short*)(w + o); o += 64 * 64 * 2;
    float* Cmat = (float*)(w + o); o += 64 * 67 * 4;
    float* b4p  = (float*)(w + o); o += 68 * 4;
    o = (o + 15) & ~(size_t)15;
    float4* Abuf  = (float4*)(w + o); o += (size_t)E * 16;   // binA output; becomes agg
    float4* Bbuf  = (float4*)(w + o); o += (size_t)E * 16;   // dst-sorted edge inputs
    float* agg    = (float*)Abuf;

    const int nb1 = (N + 1023) / 1024;

    hipMemsetAsync(counts, 0, (size_t)N * 4, stream);
    pack_w2_kernel<<<64, 64, 0, stream>>>(W2, Bhi, Blo);
    pack_w34_kernel<<<65, 128, 0, stream>>>(W3, b3, W4, b4, Cmat, b4p);
    count_kernel<<<(E + 255) / 256, 256, 0, stream>>>(ei, counts, E);
    scan1_kernel<<<nb1, 256, 0, stream>>>(counts, partials, N);
    scan2_kernel<<<1, 256, 0, stream>>>(partials, nb1, offsets, N);
    scan3_kernel<<<nb1, 256, 0, stream>>>(counts, partials, offsets, N);
    init_bcur_kernel<<<1, 256, 0, stream>>>(offsets, bcur, NB);
    binA_kernel<<<(E + CH - 1) / CH, 256, 0, stream>>>(ei, x, ea, bcur, Abuf, E, NB);
    binB_kernel<<<NB, 256, 0, stream>>>(Abuf, offsets, Bbuf, N);
    hipMemsetAsync(agg, 0, (size_t)N * HID * 4, stream);     // A is dead; reuse as agg
    edge_mlp_kernel<<<(E + 127) / 128, 128, 0, stream>>>(Bbuf, W1, b1, Bhi, Blo, b2, agg, E);
    node_kernel<<<(N + 255) / 256, 256, 0, stream>>>(x, u, batch, W4, W5, b5, Cmat, b4p,
                                                     agg, counts, (float*)d_out, N);
}